// Round 6
// baseline (1034.849 us; speedup 1.0000x reference)
//
#include <hip/hip_runtime.h>
#include <hip/hip_bf16.h>
#include <math.h>

// ---------------------------------------------------------------------------
// DeepSeekV3 MLA forward, bf16 MFMA pipeline.  Workspace budget: 237.0 MB.
// B=2, S=2048, H=32, DN=128, DR=64, DV=128, HID=4096, QR=1536, KVR=512
// ---------------------------------------------------------------------------

typedef __attribute__((ext_vector_type(8))) short s16x8;   // 8 x bf16 (4 VGPR)
typedef __attribute__((ext_vector_type(4))) float f32x4;
typedef __attribute__((ext_vector_type(4))) unsigned short u16x4;

#define DEV __device__ __forceinline__

constexpr int Bc = 2, Sc = 2048, Tc = Bc * Sc;     // tokens = 4096
constexpr int Hc = 32, DNc = 128, DRc = 64, DVc = 128;
constexpr int HIDc = 4096, QRc = 1536, KVRc = 512;
constexpr int DQK = DNc + DRc;                      // 192

DEV unsigned short f2bf(float f) {
  unsigned u = __float_as_uint(f);
  return (unsigned short)((u + 0x7fffu + ((u >> 16) & 1u)) >> 16);
}
DEV float bf2f(unsigned short u) { return __uint_as_float(((unsigned)u) << 16); }

DEV void gll16(const void* g, void* l) {
  __builtin_amdgcn_global_load_lds((const __attribute__((address_space(1))) void*)g,
                                   (__attribute__((address_space(3))) void*)l, 16, 0, 0);
}
DEV f32x4 mfma_bf16(s16x8 a, s16x8 b, f32x4 c) {
  return __builtin_amdgcn_mfma_f32_16x16x32_bf16(a, b, c, 0, 0, 0);
}
DEV unsigned cvt_pk_bf16(float a, float b) {     // lo=bf16(a), hi=bf16(b)
  unsigned r;
  asm("v_cvt_pk_bf16_f32 %0, %1, %2" : "=v"(r) : "v"(a), "v"(b));
  return r;
}

// ---------------------------------------------------------------------------
// cast fp32 -> bf16, 4 elems/thread
// ---------------------------------------------------------------------------
__global__ __launch_bounds__(256) void cast_k(const float* __restrict__ in,
                                              unsigned short* __restrict__ out, long n) {
  long i = ((long)blockIdx.x * 256 + threadIdx.x) * 4;
  if (i >= n) return;
  float4 v = *(const float4*)(in + i);
  u16x4 o;
  o.x = f2bf(v.x); o.y = f2bf(v.y); o.z = f2bf(v.z); o.w = f2bf(v.w);
  *(u16x4*)(out + i) = o;
}

// ---------------------------------------------------------------------------
// RMSNorm, in-place on bf16, one block per row
// ---------------------------------------------------------------------------
template <int COLS>
__global__ __launch_bounds__(256) void rmsnorm_bf_k(unsigned short* __restrict__ x,
                                                    const float* __restrict__ w) {
  const int row = blockIdx.x;
  unsigned short* p = x + (size_t)row * COLS;
  float ss = 0.f;
  for (int c = threadIdx.x * 8; c < COLS; c += 2048) {
    s16x8 v = *(const s16x8*)&p[c];
    #pragma unroll
    for (int j = 0; j < 8; ++j) { const float f = bf2f((unsigned short)v[j]); ss += f * f; }
  }
  #pragma unroll
  for (int off = 1; off < 64; off <<= 1) ss += __shfl_xor(ss, off, 64);
  __shared__ float sred[4];
  if ((threadIdx.x & 63) == 0) sred[threadIdx.x >> 6] = ss;
  __syncthreads();
  const float inv = rsqrtf((sred[0] + sred[1] + sred[2] + sred[3]) / (float)COLS + 1e-6f);
  for (int c = threadIdx.x * 8; c < COLS; c += 2048) {
    s16x8 v = *(const s16x8*)&p[c];
    s16x8 o;
    #pragma unroll
    for (int j = 0; j < 8; ++j)
      o[j] = (short)f2bf(bf2f((unsigned short)v[j]) * inv * w[c + j]);
    *(s16x8*)&p[c] = o;
  }
}

// ---------------------------------------------------------------------------
// GEMM (small-N fallback): C[M,N] = A[M,K] * B[N,K]^T, m97-style 128x128 tile.
// ---------------------------------------------------------------------------
template <bool OUTF32>
__global__ __launch_bounds__(256, 2) void gemm_bt(const unsigned short* __restrict__ A,
                                                  const unsigned short* __restrict__ B,
                                                  void* __restrict__ Cout,
                                                  int M, int N, int K) {
  __shared__ unsigned short As[128 * 64];
  __shared__ unsigned short Bs[128 * 64];
  const int tid = threadIdx.x;
  const int w = tid >> 6, l = tid & 63;
  const int lo = l & 15, hi = l >> 4;
  const int wr = w >> 1, wc = w & 1;
  const int m0 = blockIdx.y * 128, n0 = blockIdx.x * 128;
  const int srow = l >> 3;          // row within 8-row staging group
  const int scol = (l & 7) * 8;     // element col within BK
  f32x4 acc[4][4] = {};

  for (int kt = 0; kt < K; kt += 64) {
    __syncthreads();
    #pragma unroll
    for (int i = 0; i < 4; ++i) {
      const int rb = (w * 4 + i) * 8;
      gll16(A + (size_t)(m0 + rb + srow) * K + kt + scol, (void*)&As[rb * 64]);
      gll16(B + (size_t)(n0 + rb + srow) * K + kt + scol, (void*)&Bs[rb * 64]);
    }
    __syncthreads();

    s16x8 af[2][4], bfr[2][4];
    #pragma unroll
    for (int kk = 0; kk < 2; ++kk)
      #pragma unroll
      for (int x = 0; x < 4; ++x) {
        af[kk][x]  = *(const s16x8*)&As[(wr * 64 + x * 16 + lo) * 64 + kk * 32 + hi * 8];
        bfr[kk][x] = *(const s16x8*)&Bs[(wc * 64 + x * 16 + lo) * 64 + kk * 32 + hi * 8];
      }
    #pragma unroll
    for (int kk = 0; kk < 2; ++kk)
      #pragma unroll
      for (int m = 0; m < 4; ++m)
        #pragma unroll
        for (int n = 0; n < 4; ++n)
          acc[m][n] = mfma_bf16(af[kk][m], bfr[kk][n], acc[m][n]);
  }

  #pragma unroll
  for (int m = 0; m < 4; ++m)
    #pragma unroll
    for (int n = 0; n < 4; ++n)
      #pragma unroll
      for (int r = 0; r < 4; ++r) {
        const int row = m0 + wr * 64 + m * 16 + hi * 4 + r;
        const int col = n0 + wc * 64 + n * 16 + lo;
        const float v = acc[m][n][r];
        if (OUTF32) ((float*)Cout)[(size_t)row * N + col] = v;
        else ((unsigned short*)Cout)[(size_t)row * N + col] = f2bf(v);
      }
}

// ---------------------------------------------------------------------------
// GEMM main path: counted-vmcnt 3-buffer pipeline (T2+T4+T5).
// BM=128, BN=256, BK=64.  512 thr = 8 waves (2M x 4N), 64x64 out per wave.
// LDS: 3 K-tile buffers (A 16KB + B 32KB each) = 144 KB, 1 block/CU.
// Iter t: issue stage of tile t+2 into buf[(t+2)%3] (its previous occupant,
// tile t-1, finished reads at iter t-1's end barrier), then s_waitcnt
// vmcnt(12) (= tiles t+1,t+2 stay in flight -> tile t arrived), barrier,
// 4 MFMA phases (8 mfma each, setprio-wrapped), lgkm drain, end barrier.
// LDS swizzle: element col ^= (row&7)<<3, realized by pre-swizzled gll16
// SOURCE (linear dest) -- same family as attn Ks (0-conflict measured).
// ---------------------------------------------------------------------------
template <bool OUTF32>
__global__ __launch_bounds__(512, 1) void gemm8_bt(const unsigned short* __restrict__ A,
                                                   const unsigned short* __restrict__ B,
                                                   void* __restrict__ Cout,
                                                   int M, int N, int K) {
  __shared__ unsigned short As[3][128 * 64];    // 48 KB
  __shared__ unsigned short Bs[3][256 * 64];    // 96 KB
  const int tid = threadIdx.x;
  const int wv = tid >> 6, l = tid & 63;
  const int lo = l & 15, hi = l >> 4;
  const int wm = wv >> 2, wn = wv & 3;          // wave grid 2 x 4
  // bijective XCD swizzle (m204): consecutive logical tiles -> same XCD chunk
  const int nbx = N >> 8;
  const int nwg = (M >> 7) * nbx;
  const int orig = blockIdx.x;
  const int q8 = nwg >> 3, r8 = nwg & 7, xc = orig & 7, o8 = orig >> 3;
  const int wg = (xc < r8 ? xc * (q8 + 1) : r8 * (q8 + 1) + (xc - r8) * q8) + o8;
  const int bx = wg % nbx, by = wg / nbx;
  const int m0 = by * 128, n0 = bx * 256;
  const int lrow = l >> 3;                       // 0..7 within 8-row gll16 group
  const int lcol = (((l & 7) ^ lrow) << 3);      // pre-swizzled source col (elems)

  f32x4 acc[4][4] = {};
  const int NKT = K >> 6;

  auto stage = [&](int bi, int kt) {
    #pragma unroll
    for (int i = 0; i < 2; ++i) {               // A: 128 rows, wave wv -> [wv*16,+16)
      const int r0 = wv * 16 + i * 8;
      gll16(A + (size_t)(m0 + r0 + lrow) * K + kt + lcol, (void*)&As[bi][r0 * 64]);
    }
    #pragma unroll
    for (int i = 0; i < 4; ++i) {               // B: 256 rows, wave wv -> [wv*32,+32)
      const int r0 = wv * 32 + i * 8;
      gll16(B + (size_t)(n0 + r0 + lrow) * K + kt + lcol, (void*)&Bs[bi][r0 * 64]);
    }
  };

  stage(0, 0);
  if (NKT > 1) stage(1, 64);

  for (int t = 0; t < NKT; ++t) {
    const int bi = t % 3;
    if (t + 2 < NKT) stage((t + 2) % 3, (t + 2) * 64);
    __builtin_amdgcn_sched_barrier(0);
    if (t + 2 < NKT)      asm volatile("s_waitcnt vmcnt(12)" ::: "memory");
    else if (t + 1 < NKT) asm volatile("s_waitcnt vmcnt(6)" ::: "memory");
    else                  asm volatile("s_waitcnt vmcnt(0)" ::: "memory");
    __builtin_amdgcn_s_barrier();
    __builtin_amdgcn_sched_barrier(0);

    const unsigned short* Ab = As[bi];
    const unsigned short* Bb = Bs[bi];
    auto rdA = [&](int m, int kk) -> s16x8 {
      const int row = wm * 64 + m * 16 + lo;
      return *(const s16x8*)&Ab[row * 64 + ((kk * 32 + hi * 8) ^ ((row & 7) << 3))];
    };
    auto rdB = [&](int n, int kk) -> s16x8 {
      const int row = wn * 64 + n * 16 + lo;
      return *(const s16x8*)&Bb[row * 64 + ((kk * 32 + hi * 8) ^ ((row & 7) << 3))];
    };

    // ---- phase 0: load A[0,1]+B[0,1], mfma (m0,1 x n0,1)
    s16x8 a0k0 = rdA(0, 0), a0k1 = rdA(0, 1), a1k0 = rdA(1, 0), a1k1 = rdA(1, 1);
    s16x8 b0k0 = rdB(0, 0), b0k1 = rdB(0, 1), b1k0 = rdB(1, 0), b1k1 = rdB(1, 1);
    __builtin_amdgcn_sched_barrier(0);
    __builtin_amdgcn_s_setprio(1);
    acc[0][0] = mfma_bf16(a0k0, b0k0, acc[0][0]); acc[0][0] = mfma_bf16(a0k1, b0k1, acc[0][0]);
    acc[0][1] = mfma_bf16(a0k0, b1k0, acc[0][1]); acc[0][1] = mfma_bf16(a0k1, b1k1, acc[0][1]);
    acc[1][0] = mfma_bf16(a1k0, b0k0, acc[1][0]); acc[1][0] = mfma_bf16(a1k1, b0k1, acc[1][0]);
    acc[1][1] = mfma_bf16(a1k0, b1k0, acc[1][1]); acc[1][1] = mfma_bf16(a1k1, b1k1, acc[1][1]);
    __builtin_amdgcn_s_setprio(0);
    __builtin_amdgcn_sched_barrier(0);
    // ---- phase 1: load B[2,3], mfma (m0,1 x n2,3)
    s16x8 b2k0 = rdB(2, 0), b2k1 = rdB(2, 1), b3k0 = rdB(3, 0), b3k1 = rdB(3, 1);
    __builtin_amdgcn_sched_barrier(0);
    __builtin_amdgcn_s_setprio(1);
    acc[0][2] = mfma_bf16(a0k0, b2k0, acc[0][2]); acc[0][2] = mfma_bf16(a0k1, b2k1, acc[0][2]);
    acc[0][3] = mfma_bf16(a0k0, b3k0, acc[0][3]); acc[0][3] = mfma_bf16(a0k1, b3k1, acc[0][3]);
    acc[1][2] = mfma_bf16(a1k0, b2k0, acc[1][2]); acc[1][2] = mfma_bf16(a1k1, b2k1, acc[1][2]);
    acc[1][3] = mfma_bf16(a1k0, b3k0, acc[1][3]); acc[1][3] = mfma_bf16(a1k1, b3k1, acc[1][3]);
    __builtin_amdgcn_s_setprio(0);
    __builtin_amdgcn_sched_barrier(0);
    // ---- phase 2: load A[2,3], mfma (m2,3 x n2,3)
    s16x8 a2k0 = rdA(2, 0), a2k1 = rdA(2, 1), a3k0 = rdA(3, 0), a3k1 = rdA(3, 1);
    __builtin_amdgcn_sched_barrier(0);
    __builtin_amdgcn_s_setprio(1);
    acc[2][2] = mfma_bf16(a2k0, b2k0, acc[2][2]); acc[2][2] = mfma_bf16(a2k1, b2k1, acc[2][2]);
    acc[2][3] = mfma_bf16(a2k0, b3k0, acc[2][3]); acc[2][3] = mfma_bf16(a2k1, b3k1, acc[2][3]);
    acc[3][2] = mfma_bf16(a3k0, b2k0, acc[3][2]); acc[3][2] = mfma_bf16(a3k1, b2k1, acc[3][2]);
    acc[3][3] = mfma_bf16(a3k0, b3k0, acc[3][3]); acc[3][3] = mfma_bf16(a3k1, b3k1, acc[3][3]);
    __builtin_amdgcn_s_setprio(0);
    __builtin_amdgcn_sched_barrier(0);
    // ---- phase 3: no loads, mfma (m2,3 x n0,1)
    __builtin_amdgcn_s_setprio(1);
    acc[2][0] = mfma_bf16(a2k0, b0k0, acc[2][0]); acc[2][0] = mfma_bf16(a2k1, b0k1, acc[2][0]);
    acc[2][1] = mfma_bf16(a2k0, b1k0, acc[2][1]); acc[2][1] = mfma_bf16(a2k1, b1k1, acc[2][1]);
    acc[3][0] = mfma_bf16(a3k0, b0k0, acc[3][0]); acc[3][0] = mfma_bf16(a3k1, b0k1, acc[3][0]);
    acc[3][1] = mfma_bf16(a3k0, b1k0, acc[3][1]); acc[3][1] = mfma_bf16(a3k1, b1k1, acc[3][1]);
    __builtin_amdgcn_s_setprio(0);
    __builtin_amdgcn_sched_barrier(0);
    // ---- end of iter: all reads of buf[bi] done -> safe for next issue
    asm volatile("s_waitcnt lgkmcnt(0)" ::: "memory");
    __builtin_amdgcn_s_barrier();
    __builtin_amdgcn_sched_barrier(0);
  }

  #pragma unroll
  for (int m = 0; m < 4; ++m)
    #pragma unroll
    for (int n = 0; n < 4; ++n)
      #pragma unroll
      for (int r = 0; r < 4; ++r) {
        const int row = m0 + wm * 64 + m * 16 + hi * 4 + r;
        const int col = n0 + wn * 64 + n * 16 + lo;
        const float v = acc[m][n][r];
        if (OUTF32) ((float*)Cout)[(size_t)row * N + col] = v;
        else ((unsigned short*)Cout)[(size_t)row * N + col] = f2bf(v);
      }
}

// ---------------------------------------------------------------------------
// RoPE + layout pack.  q_buf[token][h*192+d] -> Qa[bh][s][192]
// ---------------------------------------------------------------------------
DEV void rope8(float pos, int j0, const s16x8& xv, const s16x8& pv, unsigned short* o) {
  #pragma unroll
  for (int j = 0; j < 8; ++j) {
    const int jj = j0 + j;
    const float inv = exp2f(-(float)(jj & 31) * 0.4152410118f);  // 10000^(-(jj&31)/32)
    const float th = pos * inv;
    float sn, cs;
    sincosf(th, &sn, &cs);
    const float x = bf2f((unsigned short)xv[j]);
    const float pr = bf2f((unsigned short)pv[j]);
    const float rt = (jj < 32) ? -pr : pr;
    o[j] = f2bf(x * cs + rt * sn);
  }
}

__global__ __launch_bounds__(256) void rope_q_k(const unsigned short* __restrict__ qb,
                                                const int* __restrict__ pos,
                                                unsigned short* __restrict__ Qa) {
  const int gid = blockIdx.x * 256 + threadIdx.x;   // Bc*Hc*Sc*24 threads
  const int chunk = gid % 24, row = gid / 24;       // row = bh*2048+s
  const int d0 = chunk * 8;
  const int bh = row >> 11, s = row & 2047;
  const int b = bh >> 5, h = bh & 31;
  const int token = b * 2048 + s;
  const unsigned short* src = qb + (size_t)token * (Hc * DQK) + h * DQK;
  unsigned short* dst = Qa + (size_t)row * DQK + d0;
  if (d0 < 128) { *(s16x8*)dst = *(const s16x8*)&src[d0]; return; }
  const int j0 = d0 - 128;
  s16x8 xv = *(const s16x8*)&src[128 + j0];
  s16x8 pv = *(const s16x8*)&src[128 + (j0 ^ 32)];
  unsigned short o[8];
  rope8((float)pos[token], j0, xv, pv, o);
  *(s16x8*)dst = *(const s16x8*)o;
}

__global__ __launch_bounds__(256) void rope_k_k(const unsigned short* __restrict__ kvb,
                                                const unsigned short* __restrict__ krb,
                                                const int* __restrict__ pos,
                                                unsigned short* __restrict__ Ka) {
  const int gid = blockIdx.x * 256 + threadIdx.x;
  const int chunk = gid % 24, row = gid / 24;
  const int d0 = chunk * 8;
  const int bh = row >> 11, s = row & 2047;
  const int b = bh >> 5, h = bh & 31;
  const int token = b * 2048 + s;
  unsigned short* dst = Ka + (size_t)row * DQK + d0;
  if (d0 < 128) {
    *(s16x8*)dst = *(const s16x8*)(kvb + (size_t)token * (Hc * 256) + h * 256 + d0);
    return;
  }
  const int j0 = d0 - 128;
  const unsigned short* src = krb + (size_t)token * (Hc * DRc) + h * DRc;
  s16x8 xv = *(const s16x8*)&src[j0];
  s16x8 pv = *(const s16x8*)&src[j0 ^ 32];
  unsigned short o[8];
  rope8((float)pos[token], j0, xv, pv, o);
  *(s16x8*)dst = *(const s16x8*)o;
}

// ---------------------------------------------------------------------------
// Flash attention, swapped-QK^T in-register softmax (m214/T12 style).
// ---------------------------------------------------------------------------
__global__ __launch_bounds__(512, 2) void attn_k(const unsigned short* __restrict__ Q,
                                                 const unsigned short* __restrict__ Kt,
                                                 const unsigned short* __restrict__ KV,
                                                 unsigned short* __restrict__ O) {
  __shared__ unsigned short Ks[2][64 * 192];    // 48 KB dbuf, swizzled rows
  __shared__ unsigned short Vs[2][128 * 64];    // 32 KB dbuf, V^T [dv][key] swizzled
  __shared__ unsigned short Ps[8][32 * 64];     // 32 KB, per-wave P, pitch 64
  const int bh = blockIdx.x, qblk = blockIdx.y; // bh fastest: same-bh -> same XCD
  const int b = bh >> 5, h = bh & 31;
  const int tid = threadIdx.x, w = tid >> 6, l = tid & 63;
  const int lo = l & 15, hi = l >> 4;
  const int sw = (lo & 7) << 3;                 // Ps row swizzle (row&7 == lo&7)
  const unsigned short* Qb = Q + (size_t)bh * Sc * DQK;
  const unsigned short* Kb = Kt + (size_t)bh * Sc * DQK;
  const int qrow0 = qblk * 256 + w * 32;
  const float c2 = 0.10411759f;                 // (1/sqrt(192)) * log2(e)

  s16x8 qfr[2][6];                              // B-frag: q=qrow0+qf*16+lo, d=dc*32+hi*8
  #pragma unroll
  for (int qf = 0; qf < 2; ++qf)
    #pragma unroll
    for (int dc = 0; dc < 6; ++dc)
      qfr[qf][dc] = *(const s16x8*)&Qb[(size_t)(qrow0 + qf * 16 + lo) * DQK + dc * 32 + hi * 8];

  f32x4 oacc[2][8] = {};
  float mrow[2] = {-INFINITY, -INFINITY};       // per-lane, q = qf*16+lo (log2 domain)
  float lrow[2] = {0.f, 0.f};

  s16x8 vv[2];
  auto stageK = [&](int kb, int kt) {
    #pragma unroll
    for (int i = 0; i < 3; ++i) {
      const int o = (w * 3 + i) * 1024 + l * 16;   // byte offset in 64x192 tile
      const int rr = o / 384, cc = o % 384;
      const int scc = cc ^ ((rr & 7) << 4);
      gll16(Kb + (size_t)(kt + rr) * DQK + (scc >> 1), (void*)&Ks[kb][(w * 3 + i) * 512]);
    }
  };
  auto loadV = [&](int kt) {
    #pragma unroll
    for (int it = 0; it < 2; ++it) {
      const int dv0 = (w * 2 + it) * 8;
      vv[it] = *(const s16x8*)(KV + (size_t)(b * Sc + kt + l) * (Hc * 256) + h * 256 + 128 + dv0);
    }
  };
  auto writeV = [&](int vb) {
    #pragma unroll
    for (int it = 0; it < 2; ++it) {
      const int dv0 = (w * 2 + it) * 8;
      #pragma unroll
      for (int j = 0; j < 8; ++j) {
        const int dv = dv0 + j;
        Vs[vb][(dv * 64 + l) ^ ((dv & 7) << 3)] = (unsigned short)vv[it][j];
      }
    }
  };

  constexpr int NT = Sc / 64;   // 32
  loadV(0);
  stageK(0, 0);
  writeV(0);                    // compiler inserts counted vmcnt for vv
  asm volatile("s_waitcnt vmcnt(0) lgkmcnt(0)" ::: "memory");
  __builtin_amdgcn_s_barrier();
  __builtin_amdgcn_sched_barrier(0);
  int cur = 0;

  for (int t = 0; t < NT; ++t) {
    const bool pre = (t + 1 < NT);
    // ---- prefetch issue: V first (reg), then K (gll16) -> vv wait = vmcnt(3)
    if (pre) {
      loadV((t + 1) * 64);
      __builtin_amdgcn_sched_barrier(0);
      stageK(cur ^ 1, (t + 1) * 64);
      __builtin_amdgcn_sched_barrier(0);
    }

    // ---- QK^T swapped: sc[qf][cf] = S[key=cf*16+hi*4+r][q=qf*16+lo]
    f32x4 sc[2][4] = {};
    #pragma unroll
    for (int cf = 0; cf < 4; ++cf) {
      const int krow = cf * 16 + lo;
      #pragma unroll
      for (int dc = 0; dc < 6; ++dc) {
        s16x8 kf = *(const s16x8*)&Ks[cur][(krow * 192 + dc * 32 + hi * 8) ^ ((krow & 7) << 3)];
        sc[0][cf] = mfma_bf16(kf, qfr[0][dc], sc[0][cf]);
        sc[1][cf] = mfma_bf16(kf, qfr[1][dc], sc[1][cf]);
      }
    }

    // ---- in-register online softmax per q-column
    #pragma unroll
    for (int qf = 0; qf < 2; ++qf) {
      float mx = sc[qf][0][0];
      #pragma unroll
      for (int cf = 0; cf < 4; ++cf)
        #pragma unroll
        for (int r = 0; r < 4; ++r) mx = fmaxf(mx, sc[qf][cf][r]);
      mx = fmaxf(mx, __shfl_xor(mx, 16, 64));
      mx = fmaxf(mx, __shfl_xor(mx, 32, 64));
      const float nm = fmaxf(mrow[qf], mx * c2);
      const float alpha = exp2f(mrow[qf] - nm);
      mrow[qf] = nm;
      float psum = 0.f;
      const int qrow = qf * 16 + lo;
      #pragma unroll
      for (int cf = 0; cf < 4; ++cf) {
        float p0 = exp2f(fmaf(sc[qf][cf][0], c2, -nm));
        float p1 = exp2f(fmaf(sc[qf][cf][1], c2, -nm));
        float p2 = exp2f(fmaf(sc[qf][cf][2], c2, -nm));
        float p3 = exp2f(fmaf(sc[qf][cf][3], c2, -nm));
        psum += (p0 + p1) + (p2 + p3);
        const int ka = cf * 16 + hi * 4;
        *(unsigned*)&Ps[w][qrow * 64 + ((ka + 0) ^ sw)] = cvt_pk_bf16(p0, p1);
        *(unsigned*)&Ps[w][qrow * 64 + ((ka + 2) ^ sw)] = cvt_pk_bf16(p2, p3);
      }
      psum += __shfl_xor(psum, 16, 64);
      psum += __shfl_xor(psum, 32, 64);
      lrow[qf] = lrow[qf] * alpha + psum;
      // alpha lives at lane (q&15); oacc rows are hi*4+r -> gather 4 alphas
      #pragma unroll
      for (int r = 0; r < 4; ++r) {
        const float ar = __shfl(alpha, hi * 4 + r, 64);
        #pragma unroll
        for (int dvf = 0; dvf < 8; ++dvf) oacc[qf][dvf][r] *= ar;
      }
    }

    // ---- PV: pa from Ps (A-frag rows = q), vb = V^T from Vs
    #pragma unroll
    for (int hf = 0; hf < 2; ++hf) {
      s16x8 pa0 = *(const s16x8*)&Ps[w][lo * 64 + ((hf * 32 + hi * 8) ^ sw)];
      s16x8 pa1 = *(const s16x8*)&Ps[w][(16 + lo) * 64 + ((hf * 32 + hi * 8) ^ sw)];
      #pragma unroll
      for (int dvf = 0; dvf < 8; ++dvf) {
        const int dv = dvf * 16 + lo;
        s16x8 vb = *(const s16x8*)&Vs[cur][(dv * 64 + hf * 32 + hi * 8) ^ ((dv & 7) << 3)];
        oacc[0][dvf] = mfma_bf16(pa0, vb, oacc[0][dvf]);
        oacc[1][dvf] = mfma_bf16(pa1, vb, oacc[1][dvf]);
      }
    }

    // ---- stage V(t+1) regs -> LDS; then single drain + raw barrier
    if (pre) writeV(cur ^ 1);
    asm volatile("s_waitcnt vmcnt(0) lgkmcnt(0)" ::: "memory");
    __builtin_amdgcn_s_barrier();
    __builtin_amdgcn_sched_barrier(0);
    cur ^= 1;
  }

  // ---- epilogue: O[token][h*128+dv] = oacc / l  (gather l across lanes)
  #pragma unroll
  for (int qf = 0; qf < 2; ++qf)
    #pragma unroll
    for (int r = 0; r < 4; ++r) {
      const float linv = 1.f / __shfl(lrow[qf], hi * 4 + r, 64);
      const int q = qrow0 + qf * 16 + hi * 4 + r;
      #pragma unroll
      for (int dvf = 0; dvf < 8; ++dvf)
        O[(size_t)(b * Sc + q) * (Hc * DVc) + h * DVc + dvf * 16 + lo] =
            f2bf(oacc[qf][dvf][r] * linv);
    }
}

// ---------------------------------------------------------------------------
extern "C" void kernel_launch(void* const* d_in, const int* in_sizes, int n_in,
                              void* d_out, int out_size, void* d_ws, size_t ws_size,
                              hipStream_t stream) {
  const float* hs      = (const float*)d_in[0];
  const int*   posids  = (const int*)d_in[1];
  const float* qa_w    = (const float*)d_in[2];
  const float* qa_ln   = (const float*)d_in[3];
  const float* qb_w    = (const float*)d_in[4];
  const float* kva_w   = (const float*)d_in[5];
  const float* kva_ln  = (const float*)d_in[6];
  const float* kvb_w   = (const float*)d_in[7];
  const float* kr_w    = (const float*)d_in[8];
  const float* o_w     = (const float*)d_in[9];
  float* out = (float*)d_out;

  // ---- overlaid workspace layout (total 236,978,176 B = 237.0 MB) ----
  char* ws = (char*)d_ws;
  const size_t offF  = 0;                        // 33,554,432: hs_bf -> attn_o
  const size_t offR1 = offF  + 33554432;         // 16,777,216: qa_n | kva_n -> kr_buf
  const size_t offW  = offR1 + 16777216;         // 18,874,368: weight scratch
  const size_t offD  = offW  + 18874368;         // 50,331,648: q_buf -> Ka
  const size_t offA  = offD  + 50331648;         // 67,108,864: kv_buf
  const size_t offB  = offA  + 67108864;         // 50,331,648: Qa -> w_o

  unsigned short* hs_bf  = (unsigned short*)(ws + offF);
  unsigned short* attn_o = (unsigned short*)(ws + offF);     // after kr gemm
  unsigned short* qa_n   = (unsigned short*)(ws + offR1);
  unsigned short* kva_n  = (unsigned short*)(ws + offR1 + 12582912);
  unsigned short* kr_buf = (unsigned short*)(ws + offR1);    // after kvb gemm
  unsigned short* wbuf   = (unsigned short*)(ws + offW);
  unsigned short* q_buf  = (unsigned short*)(ws + offD);
  unsigned short* Ka     = (unsigned short*)(ws + offD);     // after rope_q
  unsigned short* kv_buf = (unsigned short*)(ws + offA);
  unsigned short* Qa     = (unsigned short*)(ws + offB);
  unsigned short* w_o    = (unsigned short*)(ws + offB);     // after attn

  auto cast = [&](const float* src, unsigned short* dst, long n) {
    cast_k<<<dim3((unsigned)((n / 4 + 255) / 256)), dim3(256), 0, stream>>>(src, dst, n);
  };
  auto gemm_bf = [&](const unsigned short* A, const unsigned short* B, unsigned short* C,
                     int M, int N, int K) {
    gemm_bt<false><<<dim3(N / 128, M / 128), dim3(256), 0, stream>>>(A, B, (void*)C, M, N, K);
  };
  auto gemm8_bf = [&](const unsigned short* A, const unsigned short* B, unsigned short* C,
                      int M, int N, int K) {
    gemm8_bt<false><<<dim3((M / 128) * (N / 256)), dim3(512), 0, stream>>>(A, B, (void*)C, M, N, K);
  };
  auto gemm8_f32 = [&](const unsigned short* A, const unsigned short* B, float* C,
                       int M, int N, int K) {
    gemm8_bt<true><<<dim3((M / 128) * (N / 256)), dim3(512), 0, stream>>>(A, B, (void*)C, M, N, K);
  };

  // 1. hidden states -> bf16
  cast(hs, hs_bf, (long)Tc * HIDc);

  // 2-3. q_a proj + rmsnorm (in place, bf16)
  cast(qa_w, wbuf, (long)QRc * HIDc);
  gemm8_bf(hs_bf, wbuf, qa_n, Tc, QRc, HIDc);
  rmsnorm_bf_k<QRc><<<dim3(Tc), dim3(256), 0, stream>>>(qa_n, qa_ln);

  // 4. q_b proj
  cast(qb_w, wbuf, (long)Hc * DQK * QRc);
  gemm8_bf(qa_n, wbuf, q_buf, Tc, Hc * DQK, QRc);

  // 5-6. kv_a proj + rmsnorm (N=512: stays on 128^2 kernel for grid fill)
  cast(kva_w, wbuf, (long)KVRc * HIDc);
  gemm_bf(hs_bf, wbuf, kva_n, Tc, KVRc, HIDc);
  rmsnorm_bf_k<KVRc><<<dim3(Tc), dim3(256), 0, stream>>>(kva_n, kva_ln);

  // 7. kv_b proj
  cast(kvb_w, wbuf, (long)Hc * 256 * KVRc);
  gemm8_bf(kva_n, wbuf, kv_buf, Tc, Hc * 256, KVRc);

  // 8. k_rope proj (overwrites qa_n/kva_n region; both dead now)
  cast(kr_w, wbuf, (long)Hc * DRc * HIDc);
  gemm8_bf(hs_bf, wbuf, kr_buf, Tc, Hc * DRc, HIDc);

  // 9-10. RoPE + pack into [bh][s][d]; rope_q frees q_buf region for Ka
  const int nchunks = Bc * Hc * Sc * 24;   // 3,145,728
  rope_q_k<<<dim3(nchunks / 256), dim3(256), 0, stream>>>(q_buf, posids, Qa);
  rope_k_k<<<dim3(nchunks / 256), dim3(256), 0, stream>>>(kv_buf, kr_buf, posids, Ka);

  // 11. attention (hs_bf region now holds attn_o); grid: bh fastest for XCD/L2
  attn_k<<<dim3(Bc * Hc, Sc / 256), dim3(512), 0, stream>>>(Qa, Ka, kv_buf, attn_o);

  // 12. output projection -> fp32 d_out (w_o cast into Qa region, dead after attn)
  cast(o_w, w_o, (long)HIDc * Hc * DVc);
  gemm8_f32(attn_o, w_o, out, Tc, HIDc, Hc * DVc);

  (void)in_sizes; (void)n_in; (void)out_size; (void)ws_size;
}

// Round 7
// 877.629 us; speedup vs baseline: 1.1791x; 1.1791x over previous
//
#include <hip/hip_runtime.h>
#include <hip/hip_bf16.h>
#include <math.h>

// ---------------------------------------------------------------------------
// DeepSeekV3 MLA forward, bf16 MFMA pipeline.  Workspace: 237.0 MB (overlaid).
// B=2, S=2048, H=32, DN=128, DR=64, DV=128, HID=4096, QR=1536, KVR=512
// q_a + kv_a + k_rope fused into one [4096 x 4096 x 4096] GEMM (N = 1536+512+2048).
// ---------------------------------------------------------------------------

typedef __attribute__((ext_vector_type(8))) short s16x8;   // 8 x bf16 (4 VGPR)
typedef __attribute__((ext_vector_type(4))) float f32x4;
typedef __attribute__((ext_vector_type(4))) unsigned short u16x4;

#define DEV __device__ __forceinline__

constexpr int Bc = 2, Sc = 2048, Tc = Bc * Sc;     // tokens = 4096
constexpr int Hc = 32, DNc = 128, DRc = 64, DVc = 128;
constexpr int HIDc = 4096, QRc = 1536, KVRc = 512;
constexpr int DQK = DNc + DRc;                      // 192

DEV unsigned short f2bf(float f) {
  unsigned u = __float_as_uint(f);
  return (unsigned short)((u + 0x7fffu + ((u >> 16) & 1u)) >> 16);
}
DEV float bf2f(unsigned short u) { return __uint_as_float(((unsigned)u) << 16); }

DEV void gll16(const void* g, void* l) {
  __builtin_amdgcn_global_load_lds((const __attribute__((address_space(1))) void*)g,
                                   (__attribute__((address_space(3))) void*)l, 16, 0, 0);
}
DEV f32x4 mfma_bf16(s16x8 a, s16x8 b, f32x4 c) {
  return __builtin_amdgcn_mfma_f32_16x16x32_bf16(a, b, c, 0, 0, 0);
}
DEV unsigned cvt_pk_bf16(float a, float b) {     // lo=bf16(a), hi=bf16(b)
  unsigned r;
  asm("v_cvt_pk_bf16_f32 %0, %1, %2" : "=v"(r) : "v"(a), "v"(b));
  return r;
}

// ---------------------------------------------------------------------------
// cast fp32 -> bf16, 4 elems/thread
// ---------------------------------------------------------------------------
__global__ __launch_bounds__(256) void cast_k(const float* __restrict__ in,
                                              unsigned short* __restrict__ out, long n) {
  long i = ((long)blockIdx.x * 256 + threadIdx.x) * 4;
  if (i >= n) return;
  float4 v = *(const float4*)(in + i);
  u16x4 o;
  o.x = f2bf(v.x); o.y = f2bf(v.y); o.z = f2bf(v.z); o.w = f2bf(v.w);
  *(u16x4*)(out + i) = o;
}

// ---------------------------------------------------------------------------
// RMSNorm, in-place on bf16 columns [0,COLS) of a pitched row, 1 block/row
// ---------------------------------------------------------------------------
template <int COLS>
__global__ __launch_bounds__(256) void rmsnorm_bf_k(unsigned short* __restrict__ x,
                                                    const float* __restrict__ w,
                                                    int pitch) {
  const int row = blockIdx.x;
  unsigned short* p = x + (size_t)row * pitch;
  float ss = 0.f;
  for (int c = threadIdx.x * 8; c < COLS; c += 2048) {
    s16x8 v = *(const s16x8*)&p[c];
    #pragma unroll
    for (int j = 0; j < 8; ++j) { const float f = bf2f((unsigned short)v[j]); ss += f * f; }
  }
  #pragma unroll
  for (int off = 1; off < 64; off <<= 1) ss += __shfl_xor(ss, off, 64);
  __shared__ float sred[4];
  if ((threadIdx.x & 63) == 0) sred[threadIdx.x >> 6] = ss;
  __syncthreads();
  const float inv = rsqrtf((sred[0] + sred[1] + sred[2] + sred[3]) / (float)COLS + 1e-6f);
  for (int c = threadIdx.x * 8; c < COLS; c += 2048) {
    s16x8 v = *(const s16x8*)&p[c];
    s16x8 o;
    #pragma unroll
    for (int j = 0; j < 8; ++j)
      o[j] = (short)f2bf(bf2f((unsigned short)v[j]) * inv * w[c + j]);
    *(s16x8*)&p[c] = o;
  }
}

// ---------------------------------------------------------------------------
// GEMM: C[M,N] = A[M,K](bf16, row pitch lda) * B[N,K]^T(bf16, pitch K).
// 256x256 tile, BK=64.  512 thr = 8 waves (2M x 4N), 128x64 out per wave
// (2.67 MFMA per ds_read_b128).  LDS 128 KB: 2-deep double buffer.
// Counted vmcnt(8): stage(t+1) issued at iter top, never drained to 0 in loop.
// 4 quadrant phases per K-tile: {ds_reads, setprio(1), 16 MFMA, setprio(0),
// s_barrier} -> wave role-split so T4/T5 pay (m201 pattern).
// LDS swizzle via pre-swizzled gll16 SOURCE (linear dest), XOR (row&7)<<3.
// ---------------------------------------------------------------------------
template <bool OUTF32>
__global__ __launch_bounds__(512, 2) void gemm256_bt(const unsigned short* __restrict__ A,
                                                     int lda,
                                                     const unsigned short* __restrict__ B,
                                                     void* __restrict__ Cout,
                                                     int M, int N, int K) {
  __shared__ unsigned short As[2][256 * 64];    // 64 KB
  __shared__ unsigned short Bs[2][256 * 64];    // 64 KB
  const int tid = threadIdx.x;
  const int wv = tid >> 6, l = tid & 63;
  const int lo = l & 15, hi = l >> 4;
  const int wm = wv >> 2, wn = wv & 3;          // wave grid 2 x 4
  // bijective XCD swizzle (m204)
  const int nbx = N >> 8;
  const int nwg = (M >> 8) * nbx;
  const int orig = blockIdx.x;
  const int q8 = nwg >> 3, r8 = nwg & 7, xc = orig & 7, o8 = orig >> 3;
  const int wg = (xc < r8 ? xc * (q8 + 1) : r8 * (q8 + 1) + (xc - r8) * q8) + o8;
  const int bx = wg % nbx, by = wg / nbx;
  const int m0 = by * 256, n0 = bx * 256;
  const int lrow = l >> 3;                       // row within 8-row gll16 group
  const int lcol = (((l & 7) ^ lrow) << 3);      // pre-swizzled source col (elems)

  f32x4 acc[8][4] = {};
  const int NKT = K >> 6;

  auto stage = [&](int bi, int kt) {
    #pragma unroll
    for (int i = 0; i < 4; ++i) {               // A: rows [wv*32, wv*32+32)
      const int r0 = wv * 32 + i * 8;
      gll16(A + (size_t)(m0 + r0 + lrow) * lda + kt + lcol, (void*)&As[bi][r0 * 64]);
    }
    #pragma unroll
    for (int i = 0; i < 4; ++i) {               // B: rows [wv*32, wv*32+32)
      const int r0 = wv * 32 + i * 8;
      gll16(B + (size_t)(n0 + r0 + lrow) * K + kt + lcol, (void*)&Bs[bi][r0 * 64]);
    }
  };

  stage(0, 0);

  for (int t = 0; t < NKT; ++t) {
    const int bi = t & 1;
    if (t + 1 < NKT) stage(bi ^ 1, (t + 1) * 64);
    __builtin_amdgcn_sched_barrier(0);
    if (t + 1 < NKT) asm volatile("s_waitcnt vmcnt(8)" ::: "memory");
    else             asm volatile("s_waitcnt vmcnt(0)" ::: "memory");
    __builtin_amdgcn_s_barrier();
    __builtin_amdgcn_sched_barrier(0);

    const unsigned short* Ab = As[bi];
    const unsigned short* Bb = Bs[bi];
    auto rdA = [&](int m, int kk) -> s16x8 {
      const int row = wm * 128 + m * 16 + lo;
      return *(const s16x8*)&Ab[row * 64 + ((kk * 32 + hi * 8) ^ ((row & 7) << 3))];
    };
    auto rdB = [&](int n, int kk) -> s16x8 {
      const int row = wn * 64 + n * 16 + lo;
      return *(const s16x8*)&Bb[row * 64 + ((kk * 32 + hi * 8) ^ ((row & 7) << 3))];
    };

    s16x8 a[4][2], b0[2][2], b2[2][2];
    // ---- phase 1: A rows 0-3 + B cols 0-1, quadrant (0,0)
    #pragma unroll
    for (int m = 0; m < 4; ++m) { a[m][0] = rdA(m, 0); a[m][1] = rdA(m, 1); }
    #pragma unroll
    for (int n = 0; n < 2; ++n) { b0[n][0] = rdB(n, 0); b0[n][1] = rdB(n, 1); }
    __builtin_amdgcn_sched_barrier(0);
    __builtin_amdgcn_s_setprio(1);
    #pragma unroll
    for (int m = 0; m < 4; ++m)
      #pragma unroll
      for (int n = 0; n < 2; ++n) {
        acc[m][n] = mfma_bf16(a[m][0], b0[n][0], acc[m][n]);
        acc[m][n] = mfma_bf16(a[m][1], b0[n][1], acc[m][n]);
      }
    __builtin_amdgcn_s_setprio(0);
    __builtin_amdgcn_sched_barrier(0);
    __builtin_amdgcn_s_barrier();
    // ---- phase 2: B cols 2-3 new, quadrant (0,1)
    #pragma unroll
    for (int n = 0; n < 2; ++n) { b2[n][0] = rdB(n + 2, 0); b2[n][1] = rdB(n + 2, 1); }
    __builtin_amdgcn_sched_barrier(0);
    __builtin_amdgcn_s_setprio(1);
    #pragma unroll
    for (int m = 0; m < 4; ++m)
      #pragma unroll
      for (int n = 0; n < 2; ++n) {
        acc[m][n + 2] = mfma_bf16(a[m][0], b2[n][0], acc[m][n + 2]);
        acc[m][n + 2] = mfma_bf16(a[m][1], b2[n][1], acc[m][n + 2]);
      }
    __builtin_amdgcn_s_setprio(0);
    __builtin_amdgcn_sched_barrier(0);
    __builtin_amdgcn_s_barrier();
    // ---- phase 3: A rows 4-7 new, quadrant (1,1)
    #pragma unroll
    for (int m = 0; m < 4; ++m) { a[m][0] = rdA(m + 4, 0); a[m][1] = rdA(m + 4, 1); }
    __builtin_amdgcn_sched_barrier(0);
    __builtin_amdgcn_s_setprio(1);
    #pragma unroll
    for (int m = 0; m < 4; ++m)
      #pragma unroll
      for (int n = 0; n < 2; ++n) {
        acc[m + 4][n + 2] = mfma_bf16(a[m][0], b2[n][0], acc[m + 4][n + 2]);
        acc[m + 4][n + 2] = mfma_bf16(a[m][1], b2[n][1], acc[m + 4][n + 2]);
      }
    __builtin_amdgcn_s_setprio(0);
    __builtin_amdgcn_sched_barrier(0);
    __builtin_amdgcn_s_barrier();
    // ---- phase 4: all-reuse, quadrant (1,0); end barrier = WAR guard
    __builtin_amdgcn_s_setprio(1);
    #pragma unroll
    for (int m = 0; m < 4; ++m)
      #pragma unroll
      for (int n = 0; n < 2; ++n) {
        acc[m + 4][n] = mfma_bf16(a[m][0], b0[n][0], acc[m + 4][n]);
        acc[m + 4][n] = mfma_bf16(a[m][1], b0[n][1], acc[m + 4][n]);
      }
    __builtin_amdgcn_s_setprio(0);
    __builtin_amdgcn_sched_barrier(0);
    __builtin_amdgcn_s_barrier();
  }

  #pragma unroll
  for (int m = 0; m < 8; ++m)
    #pragma unroll
    for (int n = 0; n < 4; ++n)
      #pragma unroll
      for (int r = 0; r < 4; ++r) {
        const int row = m0 + wm * 128 + m * 16 + hi * 4 + r;
        const int col = n0 + wn * 64 + n * 16 + lo;
        const float v = acc[m][n][r];
        if (OUTF32) ((float*)Cout)[(size_t)row * N + col] = v;
        else ((unsigned short*)Cout)[(size_t)row * N + col] = f2bf(v);
      }
}

// ---------------------------------------------------------------------------
// RoPE + layout pack.  q_buf[token][h*192+d] -> Qa[bh][s][192]
// ---------------------------------------------------------------------------
DEV void rope8(float pos, int j0, const s16x8& xv, const s16x8& pv, unsigned short* o) {
  #pragma unroll
  for (int j = 0; j < 8; ++j) {
    const int jj = j0 + j;
    const float inv = exp2f(-(float)(jj & 31) * 0.4152410118f);  // 10000^(-(jj&31)/32)
    const float th = pos * inv;
    float sn, cs;
    sincosf(th, &sn, &cs);
    const float x = bf2f((unsigned short)xv[j]);
    const float pr = bf2f((unsigned short)pv[j]);
    const float rt = (jj < 32) ? -pr : pr;
    o[j] = f2bf(x * cs + rt * sn);
  }
}

__global__ __launch_bounds__(256) void rope_q_k(const unsigned short* __restrict__ qb,
                                                const int* __restrict__ pos,
                                                unsigned short* __restrict__ Qa) {
  const int gid = blockIdx.x * 256 + threadIdx.x;   // Bc*Hc*Sc*24 threads
  const int chunk = gid % 24, row = gid / 24;       // row = bh*2048+s
  const int d0 = chunk * 8;
  const int bh = row >> 11, s = row & 2047;
  const int b = bh >> 5, h = bh & 31;
  const int token = b * 2048 + s;
  const unsigned short* src = qb + (size_t)token * (Hc * DQK) + h * DQK;
  unsigned short* dst = Qa + (size_t)row * DQK + d0;
  if (d0 < 128) { *(s16x8*)dst = *(const s16x8*)&src[d0]; return; }
  const int j0 = d0 - 128;
  s16x8 xv = *(const s16x8*)&src[128 + j0];
  s16x8 pv = *(const s16x8*)&src[128 + (j0 ^ 32)];
  unsigned short o[8];
  rope8((float)pos[token], j0, xv, pv, o);
  *(s16x8*)dst = *(const s16x8*)o;
}

// krb = cbuf + 2048 (pitch HIDc): k_rope output lives in fused-GEMM columns
__global__ __launch_bounds__(256) void rope_k_k(const unsigned short* __restrict__ kvb,
                                                const unsigned short* __restrict__ krb,
                                                const int* __restrict__ pos,
                                                unsigned short* __restrict__ Ka) {
  const int gid = blockIdx.x * 256 + threadIdx.x;
  const int chunk = gid % 24, row = gid / 24;
  const int d0 = chunk * 8;
  const int bh = row >> 11, s = row & 2047;
  const int b = bh >> 5, h = bh & 31;
  const int token = b * 2048 + s;
  unsigned short* dst = Ka + (size_t)row * DQK + d0;
  if (d0 < 128) {
    *(s16x8*)dst = *(const s16x8*)(kvb + (size_t)token * (Hc * 256) + h * 256 + d0);
    return;
  }
  const int j0 = d0 - 128;
  const unsigned short* src = krb + (size_t)token * HIDc + h * DRc;
  s16x8 xv = *(const s16x8*)&src[j0];
  s16x8 pv = *(const s16x8*)&src[j0 ^ 32];
  unsigned short o[8];
  rope8((float)pos[token], j0, xv, pv, o);
  *(s16x8*)dst = *(const s16x8*)o;
}

// ---------------------------------------------------------------------------
// Flash attention, swapped-QK^T in-register softmax (m214/T12 style).
// ---------------------------------------------------------------------------
__global__ __launch_bounds__(512, 2) void attn_k(const unsigned short* __restrict__ Q,
                                                 const unsigned short* __restrict__ Kt,
                                                 const unsigned short* __restrict__ KV,
                                                 unsigned short* __restrict__ O) {
  __shared__ unsigned short Ks[2][64 * 192];    // 48 KB dbuf, swizzled rows
  __shared__ unsigned short Vs[2][128 * 64];    // 32 KB dbuf, V^T [dv][key] swizzled
  __shared__ unsigned short Ps[8][32 * 64];     // 32 KB, per-wave P, pitch 64
  const int bh = blockIdx.x, qblk = blockIdx.y; // bh fastest: same-bh -> same XCD
  const int b = bh >> 5, h = bh & 31;
  const int tid = threadIdx.x, w = tid >> 6, l = tid & 63;
  const int lo = l & 15, hi = l >> 4;
  const int sw = (lo & 7) << 3;                 // Ps row swizzle (row&7 == lo&7)
  const unsigned short* Qb = Q + (size_t)bh * Sc * DQK;
  const unsigned short* Kb = Kt + (size_t)bh * Sc * DQK;
  const int qrow0 = qblk * 256 + w * 32;
  const float c2 = 0.10411759f;                 // (1/sqrt(192)) * log2(e)

  s16x8 qfr[2][6];                              // B-frag: q=qrow0+qf*16+lo, d=dc*32+hi*8
  #pragma unroll
  for (int qf = 0; qf < 2; ++qf)
    #pragma unroll
    for (int dc = 0; dc < 6; ++dc)
      qfr[qf][dc] = *(const s16x8*)&Qb[(size_t)(qrow0 + qf * 16 + lo) * DQK + dc * 32 + hi * 8];

  f32x4 oacc[2][8] = {};
  float mrow[2] = {-INFINITY, -INFINITY};       // per-lane, q = qf*16+lo (log2 domain)
  float lrow[2] = {0.f, 0.f};

  s16x8 vv[2];
  auto stageK = [&](int kb, int kt) {
    #pragma unroll
    for (int i = 0; i < 3; ++i) {
      const int o = (w * 3 + i) * 1024 + l * 16;   // byte offset in 64x192 tile
      const int rr = o / 384, cc = o % 384;
      const int scc = cc ^ ((rr & 7) << 4);
      gll16(Kb + (size_t)(kt + rr) * DQK + (scc >> 1), (void*)&Ks[kb][(w * 3 + i) * 512]);
    }
  };
  auto loadV = [&](int kt) {
    #pragma unroll
    for (int it = 0; it < 2; ++it) {
      const int dv0 = (w * 2 + it) * 8;
      vv[it] = *(const s16x8*)(KV + (size_t)(b * Sc + kt + l) * (Hc * 256) + h * 256 + 128 + dv0);
    }
  };
  auto writeV = [&](int vb) {
    #pragma unroll
    for (int it = 0; it < 2; ++it) {
      const int dv0 = (w * 2 + it) * 8;
      #pragma unroll
      for (int j = 0; j < 8; ++j) {
        const int dv = dv0 + j;
        Vs[vb][(dv * 64 + l) ^ ((dv & 7) << 3)] = (unsigned short)vv[it][j];
      }
    }
  };

  constexpr int NT = Sc / 64;   // 32
  loadV(0);
  stageK(0, 0);
  writeV(0);                    // compiler inserts counted vmcnt for vv
  asm volatile("s_waitcnt vmcnt(0) lgkmcnt(0)" ::: "memory");
  __builtin_amdgcn_s_barrier();
  __builtin_amdgcn_sched_barrier(0);
  int cur = 0;

  for (int t = 0; t < NT; ++t) {
    const bool pre = (t + 1 < NT);
    // ---- prefetch issue: V first (reg), then K (gll16) -> vv wait = vmcnt(3)
    if (pre) {
      loadV((t + 1) * 64);
      __builtin_amdgcn_sched_barrier(0);
      stageK(cur ^ 1, (t + 1) * 64);
      __builtin_amdgcn_sched_barrier(0);
    }

    // ---- QK^T swapped: sc[qf][cf] = S[key=cf*16+hi*4+r][q=qf*16+lo]
    f32x4 sc[2][4] = {};
    #pragma unroll
    for (int cf = 0; cf < 4; ++cf) {
      const int krow = cf * 16 + lo;
      #pragma unroll
      for (int dc = 0; dc < 6; ++dc) {
        s16x8 kf = *(const s16x8*)&Ks[cur][(krow * 192 + dc * 32 + hi * 8) ^ ((krow & 7) << 3)];
        sc[0][cf] = mfma_bf16(kf, qfr[0][dc], sc[0][cf]);
        sc[1][cf] = mfma_bf16(kf, qfr[1][dc], sc[1][cf]);
      }
    }

    // ---- in-register online softmax per q-column
    #pragma unroll
    for (int qf = 0; qf < 2; ++qf) {
      float mx = sc[qf][0][0];
      #pragma unroll
      for (int cf = 0; cf < 4; ++cf)
        #pragma unroll
        for (int r = 0; r < 4; ++r) mx = fmaxf(mx, sc[qf][cf][r]);
      mx = fmaxf(mx, __shfl_xor(mx, 16, 64));
      mx = fmaxf(mx, __shfl_xor(mx, 32, 64));
      const float nm = fmaxf(mrow[qf], mx * c2);
      const float alpha = exp2f(mrow[qf] - nm);
      mrow[qf] = nm;
      float psum = 0.f;
      const int qrow = qf * 16 + lo;
      #pragma unroll
      for (int cf = 0; cf < 4; ++cf) {
        float p0 = exp2f(fmaf(sc[qf][cf][0], c2, -nm));
        float p1 = exp2f(fmaf(sc[qf][cf][1], c2, -nm));
        float p2 = exp2f(fmaf(sc[qf][cf][2], c2, -nm));
        float p3 = exp2f(fmaf(sc[qf][cf][3], c2, -nm));
        psum += (p0 + p1) + (p2 + p3);
        const int ka = cf * 16 + hi * 4;
        *(unsigned*)&Ps[w][qrow * 64 + ((ka + 0) ^ sw)] = cvt_pk_bf16(p0, p1);
        *(unsigned*)&Ps[w][qrow * 64 + ((ka + 2) ^ sw)] = cvt_pk_bf16(p2, p3);
      }
      psum += __shfl_xor(psum, 16, 64);
      psum += __shfl_xor(psum, 32, 64);
      lrow[qf] = lrow[qf] * alpha + psum;
      // alpha lives at lane (q&15); oacc rows are hi*4+r -> gather 4 alphas
      #pragma unroll
      for (int r = 0; r < 4; ++r) {
        const float ar = __shfl(alpha, hi * 4 + r, 64);
        #pragma unroll
        for (int dvf = 0; dvf < 8; ++dvf) oacc[qf][dvf][r] *= ar;
      }
    }

    // ---- PV: pa from Ps (A-frag rows = q), vb = V^T from Vs
    #pragma unroll
    for (int hf = 0; hf < 2; ++hf) {
      s16x8 pa0 = *(const s16x8*)&Ps[w][lo * 64 + ((hf * 32 + hi * 8) ^ sw)];
      s16x8 pa1 = *(const s16x8*)&Ps[w][(16 + lo) * 64 + ((hf * 32 + hi * 8) ^ sw)];
      #pragma unroll
      for (int dvf = 0; dvf < 8; ++dvf) {
        const int dv = dvf * 16 + lo;
        s16x8 vb = *(const s16x8*)&Vs[cur][(dv * 64 + hf * 32 + hi * 8) ^ ((dv & 7) << 3)];
        oacc[0][dvf] = mfma_bf16(pa0, vb, oacc[0][dvf]);
        oacc[1][dvf] = mfma_bf16(pa1, vb, oacc[1][dvf]);
      }
    }

    // ---- stage V(t+1) regs -> LDS; then single drain + raw barrier
    if (pre) writeV(cur ^ 1);
    asm volatile("s_waitcnt vmcnt(0) lgkmcnt(0)" ::: "memory");
    __builtin_amdgcn_s_barrier();
    __builtin_amdgcn_sched_barrier(0);
    cur ^= 1;
  }

  // ---- epilogue: O[token][h*128+dv] = oacc / l  (gather l across lanes)
  #pragma unroll
  for (int qf = 0; qf < 2; ++qf)
    #pragma unroll
    for (int r = 0; r < 4; ++r) {
      const float linv = 1.f / __shfl(lrow[qf], hi * 4 + r, 64);
      const int q = qrow0 + qf * 16 + hi * 4 + r;
      #pragma unroll
      for (int dvf = 0; dvf < 8; ++dvf)
        O[(size_t)(b * Sc + q) * (Hc * DVc) + h * DVc + dvf * 16 + lo] =
            f2bf(oacc[qf][dvf][r] * linv);
    }
}

// ---------------------------------------------------------------------------
extern "C" void kernel_launch(void* const* d_in, const int* in_sizes, int n_in,
                              void* d_out, int out_size, void* d_ws, size_t ws_size,
                              hipStream_t stream) {
  const float* hs      = (const float*)d_in[0];
  const int*   posids  = (const int*)d_in[1];
  const float* qa_w    = (const float*)d_in[2];
  const float* qa_ln   = (const float*)d_in[3];
  const float* qb_w    = (const float*)d_in[4];
  const float* kva_w   = (const float*)d_in[5];
  const float* kva_ln  = (const float*)d_in[6];
  const float* kvb_w   = (const float*)d_in[7];
  const float* kr_w    = (const float*)d_in[8];
  const float* o_w     = (const float*)d_in[9];
  float* out = (float*)d_out;

  // ---- overlaid workspace (total 236,978,176 B = 237.0 MB, same as proven) ----
  char* ws = (char*)d_ws;
  const size_t offF = 0;                    // 33,554,432: hs_bf -> w_qb -> w_kvb -> attn_o
  const size_t offR = offF + 33554432;      // 35,651,584: cbuf (33.5M used)
  const size_t offD = offR + 35651584;      // 50,331,648: q_buf -> Ka
  const size_t offA = offD + 50331648;      // 67,108,864: kv_buf
  const size_t offB = offA + 67108864;      // 50,331,648: cw -> Qa -> w_o

  unsigned short* hs_bf  = (unsigned short*)(ws + offF);
  unsigned short* w_qb   = (unsigned short*)(ws + offF);   // after fused gemm
  unsigned short* w_kvb  = (unsigned short*)(ws + offF);   // after q_b gemm
  unsigned short* attn_o = (unsigned short*)(ws + offF);   // after kv_b gemm (pre-attn)
  unsigned short* cbuf   = (unsigned short*)(ws + offR);   // [qa_n | kva_n | kr], pitch 4096
  unsigned short* q_buf  = (unsigned short*)(ws + offD);
  unsigned short* Ka     = (unsigned short*)(ws + offD);   // after rope_q
  unsigned short* kv_buf = (unsigned short*)(ws + offA);
  unsigned short* cw     = (unsigned short*)(ws + offB);   // fused weights [4096][4096]
  unsigned short* Qa     = (unsigned short*)(ws + offB);   // after fused gemm
  unsigned short* w_o    = (unsigned short*)(ws + offB);   // after attn

  auto cast = [&](const float* src, unsigned short* dst, long n) {
    cast_k<<<dim3((unsigned)((n / 4 + 255) / 256)), dim3(256), 0, stream>>>(src, dst, n);
  };
  auto g256_bf = [&](const unsigned short* A, int lda, const unsigned short* B,
                     unsigned short* C, int M, int N, int K) {
    gemm256_bt<false><<<dim3((M / 256) * (N / 256)), dim3(512), 0, stream>>>(A, lda, B, (void*)C, M, N, K);
  };
  auto g256_f32 = [&](const unsigned short* A, int lda, const unsigned short* B,
                      float* C, int M, int N, int K) {
    gemm256_bt<true><<<dim3((M / 256) * (N / 256)), dim3(512), 0, stream>>>(A, lda, B, (void*)C, M, N, K);
  };

  // 1. hidden states -> bf16
  cast(hs, hs_bf, (long)Tc * HIDc);

  // 2. fused a-projection weights: [qa(1536) | kva(512) | kr(2048)] x 4096
  cast(qa_w,  cw,                              (long)QRc * HIDc);
  cast(kva_w, cw + (size_t)QRc * HIDc,         (long)KVRc * HIDc);
  cast(kr_w,  cw + (size_t)(QRc + KVRc) * HIDc,(long)Hc * DRc * HIDc);

  // 3. fused a-projection GEMM: cbuf[4096][4096] = hs_bf x cw^T  (256 blocks)
  g256_bf(hs_bf, HIDc, cw, cbuf, Tc, HIDc, HIDc);

  // 4. RMSNorms in place on pitched columns
  rmsnorm_bf_k<QRc><<<dim3(Tc), dim3(256), 0, stream>>>(cbuf, qa_ln, HIDc);
  rmsnorm_bf_k<KVRc><<<dim3(Tc), dim3(256), 0, stream>>>(cbuf + QRc, kva_ln, HIDc);

  // 5. q_b proj (A = qa_n columns of cbuf)
  cast(qb_w, w_qb, (long)Hc * DQK * QRc);
  g256_bf(cbuf, HIDc, w_qb, q_buf, Tc, Hc * DQK, QRc);

  // 6. kv_b proj (A = kva_n columns of cbuf)
  cast(kvb_w, w_kvb, (long)Hc * 256 * KVRc);
  g256_bf(cbuf + QRc, HIDc, w_kvb, kv_buf, Tc, Hc * 256, KVRc);

  // 7. RoPE + pack into [bh][s][d]; rope_q frees q_buf region for Ka
  const int nchunks = Bc * Hc * Sc * 24;   // 3,145,728
  rope_q_k<<<dim3(nchunks / 256), dim3(256), 0, stream>>>(q_buf, posids, Qa);
  rope_k_k<<<dim3(nchunks / 256), dim3(256), 0, stream>>>(kv_buf, cbuf + QRc + KVRc, posids, Ka);

  // 8. attention (offF region now holds attn_o); grid: bh fastest for XCD/L2
  attn_k<<<dim3(Bc * Hc, Sc / 256), dim3(512), 0, stream>>>(Qa, Ka, kv_buf, attn_o);

  // 9. output projection -> fp32 d_out (w_o cast into Qa region, dead after attn)
  cast(o_w, w_o, (long)HIDc * Hc * DVc);
  g256_f32(attn_o, Hc * DVc, w_o, out, Tc, HIDc, Hc * DVc);

  (void)in_sizes; (void)n_in; (void)out_size; (void)ws_size;
}